// Round 1
// 536.134 us; speedup vs baseline: 1.1167x; 1.1167x over previous
//
#include <hip/hip_runtime.h>
#include <cstdint>

typedef __bf16 bf16;
typedef __bf16 bf16x8 __attribute__((ext_vector_type(8)));
typedef float f32x4 __attribute__((ext_vector_type(4)));

#define AS1 __attribute__((address_space(1)))
#define AS3 __attribute__((address_space(3)))

// Async global->LDS, 16B per lane. LDS dest must be wave-uniform base;
// HW writes lane i at base + i*16 (m97/m104 semantics).
__device__ __forceinline__ void load16_lds(const void* gp, void* lds_base_wave_uniform) {
    __builtin_amdgcn_global_load_lds((AS1 void*)((void*)gp),
                                     (AS3 void*)lds_base_wave_uniform, 16, 0, 0);
}

// ---------------------------------------------------------------------------
// fp32 -> (hi, lo) bf16 planes.
// ---------------------------------------------------------------------------
__global__ __launch_bounds__(256) void split_planes(const float* __restrict__ src,
                                                    bf16* __restrict__ h,
                                                    bf16* __restrict__ l, int n)
{
    const int stride = gridDim.x * blockDim.x;
    for (int i = blockIdx.x * blockDim.x + threadIdx.x; i < n; i += stride) {
        float v = src[i];
        bf16 hh = (bf16)v;
        h[i] = hh;
        l[i] = (bf16)(v - (float)hh);
    }
}

// ---------------------------------------------------------------------------
// LN1 -> xres (fp32, x rows only); LN_att(LN1) -> h hi/lo planes (all rows).
// ---------------------------------------------------------------------------
__global__ __launch_bounds__(256) void prep_ln(
    const float* __restrict__ x, const float* __restrict__ memory,
    const float* __restrict__ g1, const float* __restrict__ b1,
    const float* __restrict__ ga, const float* __restrict__ ba,
    float* __restrict__ xres, bf16* __restrict__ hH, bf16* __restrict__ hL)
{
    const int row = blockIdx.x;            // 0..6271
    const int b = row / 1568, l = row - b * 1568;
    const float* src = (l < 784) ? (memory + ((size_t)b * 1024 + l) * 768)
                                 : (x + ((size_t)b * 784 + (l - 784)) * 768);
    const int t = threadIdx.x, lane = t & 63, wv = t >> 6;
    __shared__ float red[8];

    float v[3];
#pragma unroll
    for (int i = 0; i < 3; ++i) v[i] = src[i * 256 + t];

    float s = v[0] + v[1] + v[2];
    float s2 = v[0] * v[0] + v[1] * v[1] + v[2] * v[2];
#pragma unroll
    for (int off = 1; off < 64; off <<= 1) { s += __shfl_xor(s, off, 64); s2 += __shfl_xor(s2, off, 64); }
    if (lane == 0) { red[wv] = s; red[4 + wv] = s2; }
    __syncthreads();
    s = red[0] + red[1] + red[2] + red[3];
    s2 = red[4] + red[5] + red[6] + red[7];
    float mu = s * (1.0f / 768.0f);
    float var = s2 * (1.0f / 768.0f) - mu * mu;
    float rs = rsqrtf(fmaxf(var, 0.0f) + 1e-5f);

    float w[3];
#pragma unroll
    for (int i = 0; i < 3; ++i) {
        int c = i * 256 + t;
        w[i] = (v[i] - mu) * rs * g1[c] + b1[c];
    }
    if (l >= 784) {
        float* xr = xres + ((size_t)b * 784 + (l - 784)) * 768;
#pragma unroll
        for (int i = 0; i < 3; ++i) xr[i * 256 + t] = w[i];
    }

    s = w[0] + w[1] + w[2];
    s2 = w[0] * w[0] + w[1] * w[1] + w[2] * w[2];
#pragma unroll
    for (int off = 1; off < 64; off <<= 1) { s += __shfl_xor(s, off, 64); s2 += __shfl_xor(s2, off, 64); }
    __syncthreads();
    if (lane == 0) { red[wv] = s; red[4 + wv] = s2; }
    __syncthreads();
    s = red[0] + red[1] + red[2] + red[3];
    s2 = red[4] + red[5] + red[6] + red[7];
    float mu2 = s * (1.0f / 768.0f);
    float var2 = s2 * (1.0f / 768.0f) - mu2 * mu2;
    float rs2 = rsqrtf(fmaxf(var2, 0.0f) + 1e-5f);

    bf16* hh_ = hH + (size_t)row * 768;
    bf16* hl_ = hL + (size_t)row * 768;
#pragma unroll
    for (int i = 0; i < 3; ++i) {
        int c = i * 256 + t;
        float hv = (w[i] - mu2) * rs2 * ga[c] + ba[c];
        bf16 hvh = (bf16)hv;
        hh_[c] = hvh;
        hl_[c] = (bf16)(hv - (float)hvh);
    }
}

// ---------------------------------------------------------------------------
// Plane GEMM with async global->LDS staging (width 16, m97 pattern).
// C = A*B^T; A/B as bf16 hi/lo planes; 128x128 tile, BK=32, 4 waves x 64x64.
// MODE 0: planes out. 1: fp32 acc+bias. 2: silu planes out. 3: fp32 acc+bias+resid.
// ---------------------------------------------------------------------------
template <int MODE>
__global__ __launch_bounds__(256, 2) void gemm_pl(
    const bf16* __restrict__ Ah, const bf16* __restrict__ Al,
    const bf16* __restrict__ Bh, const bf16* __restrict__ Bl,
    int M, int N, int K,
    const float* __restrict__ bias, const float* __restrict__ resid,
    float* __restrict__ Cf, bf16* __restrict__ Ch, bf16* __restrict__ Cl)
{
    __shared__ __align__(16) bf16 Ahs[128 * 32], Als[128 * 32];
    __shared__ __align__(16) bf16 Bhs[128 * 32], Bls[128 * 32];
    const int t = threadIdx.x, lane = t & 63, wv = t >> 6;
    const int row0 = blockIdx.y * 128, col0 = blockIdx.x * 128;
    const int ro = (wv >> 1) * 64, co = (wv & 1) * 64;

    f32x4 acc[4][4] = {};

    for (int k0 = 0; k0 < K; k0 += 32) {
#pragma unroll
        for (int it = 0; it < 2; ++it) {
            int f = it * 256 + t;
            int r = f >> 2, kc = (f & 3) * 8;
            int ra = row0 + r; if (ra >= M) ra = M - 1;
            size_t oa = (size_t)ra * K + k0 + kc;
            size_t ob = (size_t)(col0 + r) * K + k0 + kc;
            // wave-uniform LDS base (lane offset applied by HW: +lane*16B)
            size_t lb = (size_t)(it * 256 + wv * 64) * 8;
            load16_lds(Ah + oa, Ahs + lb);
            load16_lds(Al + oa, Als + lb);
            load16_lds(Bh + ob, Bhs + lb);
            load16_lds(Bl + ob, Bls + lb);
        }
        asm volatile("s_waitcnt vmcnt(0)" ::: "memory");
        __syncthreads();
        bf16x8 ah[4], al[4], bh[4], bl[4];
#pragma unroll
        for (int i = 0; i < 4; ++i) {
            int o = (ro + i * 16 + (lane & 15)) * 32 + (lane >> 4) * 8;
            ah[i] = *(const bf16x8*)&Ahs[o];
            al[i] = *(const bf16x8*)&Als[o];
        }
#pragma unroll
        for (int j = 0; j < 4; ++j) {
            int o = (co + j * 16 + (lane & 15)) * 32 + (lane >> 4) * 8;
            bh[j] = *(const bf16x8*)&Bhs[o];
            bl[j] = *(const bf16x8*)&Bls[o];
        }
#pragma unroll
        for (int i = 0; i < 4; ++i)
#pragma unroll
            for (int j = 0; j < 4; ++j) {
                acc[i][j] = __builtin_amdgcn_mfma_f32_16x16x32_bf16(al[i], bh[j], acc[i][j], 0, 0, 0);
                acc[i][j] = __builtin_amdgcn_mfma_f32_16x16x32_bf16(ah[i], bl[j], acc[i][j], 0, 0, 0);
                acc[i][j] = __builtin_amdgcn_mfma_f32_16x16x32_bf16(ah[i], bh[j], acc[i][j], 0, 0, 0);
            }
        __syncthreads();
    }

#pragma unroll
    for (int i = 0; i < 4; ++i)
#pragma unroll
        for (int j = 0; j < 4; ++j)
#pragma unroll
            for (int r = 0; r < 4; ++r) {
                int row = row0 + ro + i * 16 + (lane >> 4) * 4 + r;
                int col = col0 + co + j * 16 + (lane & 15);
                if (row >= M) continue;
                float v = acc[i][j][r];
                size_t idx = (size_t)row * N + col;
                if (MODE == 0) {
                    bf16 hh = (bf16)v;
                    Ch[idx] = hh; Cl[idx] = (bf16)(v - (float)hh);
                } else if (MODE == 1) {
                    Cf[idx] = v + bias[col];
                } else if (MODE == 2) {
                    v += bias[col];
                    v = v / (1.0f + __expf(-v));
                    bf16 hh = (bf16)v;
                    Ch[idx] = hh; Cl[idx] = (bf16)(v - (float)hh);
                } else {
                    Cf[idx] = v + bias[col] + resid[idx];
                }
            }
}

// ---------------------------------------------------------------------------
// Flash attention, pipelined. Grid: x = hh + 12*b (48), y = w*4+g (16).
//
// vs previous version (140 us, MfmaUtil 7.5%, 1.58e7 LDS conflicts):
//  - deferred softmax: logits S~N(0,1) (LN'd inputs, max<~7 over all pairs),
//    so no max subtraction -> no running max, no alpha rescale, and the
//    16-lane sum reduce moves to the epilogue. Zero in-loop shuffles.
//  - single barrier per K-tile: K staged via global_load_lds (pre-swizzled
//    per-lane SOURCE, linear LDS dest - m173), V reg-prefetched at phase top,
//    written to the alternate buffer at phase end (m97 issue-early/drain-late).
//  - V-transpose write conflict fix: key index XOR'd with ((d>>3)&3)*8
//    (bijective, order-preserving for 8-chunks) -> writes 16-way -> 2-way.
//  - QK MFMAs split into 4 independent depth-3 chains.
// ---------------------------------------------------------------------------
__global__ __launch_bounds__(256, 3) void attn_kernel(
    const bf16* __restrict__ qh_, const bf16* __restrict__ ql_,
    bf16* __restrict__ oh_, bf16* __restrict__ ol_)
{
    const int hh = blockIdx.x % 12, b = blockIdx.x / 12;
    const int w = blockIdx.y >> 2, g = blockIdx.y & 3;
    const int kmax = (5 + w) * 196, nkt = (kmax + 31) / 32;
    const int t = threadIdx.x, lane = t & 63, wv = t >> 6;
    const int tile = g * 4 + wv;                  // 0..15; >12 idle (wave-uniform)
    const int l15 = lane & 15, q8 = lane >> 4;

    __shared__ __align__(16) bf16 Ks_h[2][32 * 64], Ks_l[2][32 * 64];
    __shared__ __align__(16) bf16 Vt_h[2][64 * 40];
    __shared__ __align__(16) bf16 Pl_h[4][16 * 40];

    const size_t bbase = (size_t)b * 1568 * 2304;

    // staging geometry: thread t covers K/V row srow, col chunk sc8.
    const int srow = t >> 3;                      // 0..31 (wave wv: rows wv*8..+7)
    const int sc8 = (t & 7) * 8;
    // K: LDS dest is linear (global_load_lds), so pre-swizzle the SOURCE col.
    const int scsrc = sc8 ^ ((srow & 7) * 8);

    // Q fragments (held in registers for the whole kernel)
    int tcl = tile > 12 ? 12 : tile;
    int qr0 = tcl * 16 + l15; if (qr0 > 195) qr0 = 195;
    const size_t qoff = bbase + (size_t)(784 + w * 196 + qr0) * 2304 + hh * 64 + q8 * 8;
    bf16x8 qfh[2], qfl[2];
#pragma unroll
    for (int p = 0; p < 2; ++p) {
        qfh[p] = *(const bf16x8*)(qh_ + qoff + p * 32);
        qfl[p] = *(const bf16x8*)(ql_ + qoff + p * 32);
    }

    float l_i[4] = {0.f, 0.f, 0.f, 0.f};
    f32x4 oacc[4];
#pragma unroll
    for (int nd = 0; nd < 4; ++nd) oacc[nd] = f32x4{0.f, 0.f, 0.f, 0.f};

    // issue staging for K-tile kt2 into buffer bufn; V -> vreg (not yet in LDS)
    auto stage_issue = [&](int kt2, int bufn, bf16x8& vreg) {
        const size_t kb = bbase + (size_t)(kt2 * 32 + srow) * 2304 + 768 + (size_t)hh * 64;
        load16_lds(qh_ + kb + scsrc, &Ks_h[bufn][wv * 512]);
        load16_lds(ql_ + kb + scsrc, &Ks_l[bufn][wv * 512]);
        vreg = *(const bf16x8*)(qh_ + kb + 768 + sc8);
    };
    // transposed V write, key-XOR swizzled (2-way banks instead of 16-way)
    auto write_V = [&](int bufn, const bf16x8& vreg) {
#pragma unroll
        for (int j = 0; j < 8; ++j) {
            int d = sc8 + j;
            int keyx = srow ^ (((d >> 3) & 3) * 8);
            Vt_h[bufn][d * 40 + keyx] = vreg[j];
        }
    };

    // ---- prologue: stage tile 0 into buffer 0
    {
        bf16x8 v0;
        stage_issue(0, 0, v0);
        write_V(0, v0);                            // data dep inserts vmcnt wait
        asm volatile("s_waitcnt vmcnt(0)" ::: "memory");
        __syncthreads();
    }

    const float CEXP = 0.18033688011112042f;       // 0.125 * log2(e)

    for (int kt = 0; kt < nkt; ++kt) {
        const int cur = kt & 1, nxt = cur ^ 1;
        int kt2 = kt + 1; if (kt2 >= nkt) kt2 = nkt - 1;   // clamp (no OOB)
        bf16x8 vnext;
        stage_issue(kt2, nxt, vnext);              // overlaps with compute below

        if (tile <= 12) {
            bf16x8 kfh[2][2], kfl[2][2], vth[4];
#pragma unroll
            for (int nb = 0; nb < 2; ++nb)
#pragma unroll
                for (int p = 0; p < 2; ++p) {
                    int row = nb * 16 + l15;
                    int c = (p * 32 + q8 * 8) ^ ((row & 7) * 8);
                    kfh[nb][p] = *(const bf16x8*)&Ks_h[cur][row * 64 + c];
                    kfl[nb][p] = *(const bf16x8*)&Ks_l[cur][row * 64 + c];
                }
#pragma unroll
            for (int nd = 0; nd < 4; ++nd) {
                int d = nd * 16 + l15;
                int k8 = (q8 * 8) ^ (((d >> 3) & 3) * 8);
                vth[nd] = *(const bf16x8*)&Vt_h[cur][d * 40 + k8];
            }

            // QK^T: 4 independent depth-3 MFMA chains
            f32x4 s0a = {0.f,0.f,0.f,0.f}, s0b = {0.f,0.f,0.f,0.f};
            f32x4 s1a = {0.f,0.f,0.f,0.f}, s1b = {0.f,0.f,0.f,0.f};
            s0a = __builtin_amdgcn_mfma_f32_16x16x32_bf16(qfl[0], kfh[0][0], s0a, 0, 0, 0);
            s1a = __builtin_amdgcn_mfma_f32_16x16x32_bf16(qfl[0], kfh[1][0], s1a, 0, 0, 0);
            s0b = __builtin_amdgcn_mfma_f32_16x16x32_bf16(qfl[1], kfh[0][1], s0b, 0, 0, 0);
            s1b = __builtin_amdgcn_mfma_f32_16x16x32_bf16(qfl[1], kfh[1][1], s1b, 0, 0, 0);
            s0a = __builtin_amdgcn_mfma_f32_16x16x32_bf16(qfh[0], kfl[0][0], s0a, 0, 0, 0);
            s1a = __builtin_amdgcn_mfma_f32_16x16x32_bf16(qfh[0], kfl[1][0], s1a, 0, 0, 0);
            s0b = __builtin_amdgcn_mfma_f32_16x16x32_bf16(qfh[1], kfl[0][1], s0b, 0, 0, 0);
            s1b = __builtin_amdgcn_mfma_f32_16x16x32_bf16(qfh[1], kfl[1][1], s1b, 0, 0, 0);
            s0a = __builtin_amdgcn_mfma_f32_16x16x32_bf16(qfh[0], kfh[0][0], s0a, 0, 0, 0);
            s1a = __builtin_amdgcn_mfma_f32_16x16x32_bf16(qfh[0], kfh[1][0], s1a, 0, 0, 0);
            s0b = __builtin_amdgcn_mfma_f32_16x16x32_bf16(qfh[1], kfh[0][1], s0b, 0, 0, 0);
            s1b = __builtin_amdgcn_mfma_f32_16x16x32_bf16(qfh[1], kfh[1][1], s1b, 0, 0, 0);
            f32x4 s0 = s0a + s0b, s1 = s1a + s1b;

            // deferred softmax: p = exp(S/8), no max subtraction, no rescale
            const int key0 = kt * 32 + l15;
            const bool m0 = (key0 >= kmax), m1 = (key0 + 16 >= kmax);
#pragma unroll
            for (int r = 0; r < 4; ++r) {
                float p0 = m0 ? 0.0f : exp2f(s0[r] * CEXP);
                float p1 = m1 ? 0.0f : exp2f(s1[r] * CEXP);
                l_i[r] += p0 + p1;
                int pr = q8 * 4 + r;
                Pl_h[wv][pr * 40 + l15] = (bf16)p0;
                Pl_h[wv][pr * 40 + 16 + l15] = (bf16)p1;
            }
            asm volatile("s_waitcnt lgkmcnt(0)" ::: "memory");   // wave-private Pl RAW
            bf16x8 pfh = *(const bf16x8*)&Pl_h[wv][l15 * 40 + q8 * 8];
#pragma unroll
            for (int nd = 0; nd < 4; ++nd)
                oacc[nd] = __builtin_amdgcn_mfma_f32_16x16x32_bf16(pfh, vth[nd], oacc[nd], 0, 0, 0);
        }

        write_V(nxt, vnext);                       // waits vmcnt for vnext only here
        asm volatile("s_waitcnt vmcnt(0)" ::: "memory");
        __syncthreads();
    }

    if (tile <= 12) {
#pragma unroll
        for (int r = 0; r < 4; ++r) {
            float s = l_i[r];
#pragma unroll
            for (int off = 1; off < 16; off <<= 1) s += __shfl_xor(s, off, 64);
            int qr = tile * 16 + q8 * 4 + r;
            if (qr >= 196) continue;
            float inv = 1.0f / s;
            size_t row = (size_t)b * 784 + w * 196 + qr;
#pragma unroll
            for (int nd = 0; nd < 4; ++nd) {
                float ov = oacc[nd][r] * inv;
                bf16 oh = (bf16)ov;
                size_t idx = row * 768 + hh * 64 + nd * 16 + l15;
                oh_[idx] = oh;
                ol_[idx] = (bf16)(ov - (float)oh);
            }
        }
    }
}

// ---------------------------------------------------------------------------
// y = xres + att (fp32), y2 = LN2(y) as hi/lo planes. Block per x-row (3136).
// ---------------------------------------------------------------------------
__global__ __launch_bounds__(256) void ln2_resid(
    const float* __restrict__ xres, const float* __restrict__ att,
    const float* __restrict__ g2, const float* __restrict__ b2,
    float* __restrict__ y, bf16* __restrict__ y2H, bf16* __restrict__ y2L)
{
    const int row = blockIdx.x;
    const float* xr = xres + (size_t)row * 768;
    const float* ar = att + (size_t)row * 768;
    const int t = threadIdx.x, lane = t & 63, wv = t >> 6;
    __shared__ float red[8];

    float v[3];
    float* yr = y + (size_t)row * 768;
#pragma unroll
    for (int i = 0; i < 3; ++i) {
        int c = i * 256 + t;
        v[i] = xr[c] + ar[c];
        yr[c] = v[i];
    }
    float s = v[0] + v[1] + v[2];
    float s2 = v[0] * v[0] + v[1] * v[1] + v[2] * v[2];
#pragma unroll
    for (int off = 1; off < 64; off <<= 1) { s += __shfl_xor(s, off, 64); s2 += __shfl_xor(s2, off, 64); }
    if (lane == 0) { red[wv] = s; red[4 + wv] = s2; }
    __syncthreads();
    s = red[0] + red[1] + red[2] + red[3];
    s2 = red[4] + red[5] + red[6] + red[7];
    float mu = s * (1.0f / 768.0f);
    float var = s2 * (1.0f / 768.0f) - mu * mu;
    float rs = rsqrtf(fmaxf(var, 0.0f) + 1e-5f);

    bf16* yh = y2H + (size_t)row * 768;
    bf16* yl = y2L + (size_t)row * 768;
#pragma unroll
    for (int i = 0; i < 3; ++i) {
        int c = i * 256 + t;
        float yv = (v[i] - mu) * rs * g2[c] + b2[c];
        bf16 yvh = (bf16)yv;
        yh[c] = yvh;
        yl[c] = (bf16)(yv - (float)yvh);
    }
}

// ---------------------------------------------------------------------------
extern "C" void kernel_launch(void* const* d_in, const int* in_sizes, int n_in,
                              void* d_out, int out_size, void* d_ws, size_t ws_size,
                              hipStream_t stream)
{
    (void)in_sizes; (void)n_in; (void)out_size; (void)ws_size;
    const float* x        = (const float*)d_in[0];
    const float* memory   = (const float*)d_in[1];
    const float* ln_att_g = (const float*)d_in[2];
    const float* ln_att_b = (const float*)d_in[3];
    const float* w_qkv    = (const float*)d_in[4];
    const float* w_out    = (const float*)d_in[5];
    const float* b_out    = (const float*)d_in[6];
    const float* ln1_g    = (const float*)d_in[7];
    const float* ln1_b    = (const float*)d_in[8];
    const float* ln2_g    = (const float*)d_in[9];
    const float* ln2_b    = (const float*)d_in[10];
    const float* w1       = (const float*)d_in[11];
    const float* b1       = (const float*)d_in[12];
    const float* w2       = (const float*)d_in[13];
    const float* b2       = (const float*)d_in[14];

    // ---- workspace layout (same as R10, ~109.7 MiB) ----
    char* ws = (char*)d_ws;
    const size_t SZF  = (size_t)3136 * 768 * 4;
    const size_t SZP  = (size_t)3136 * 768 * 2;
    const size_t SZHP = (size_t)6272 * 768 * 2;
    const size_t SZQP = (size_t)6272 * 2304 * 2;
    const size_t SZFP = (size_t)3136 * 3072 * 2;

    float* xres = (float*)(ws);
    bf16* hH  = (bf16*)(ws + SZF);
    bf16* hL  = (bf16*)(ws + SZF + SZHP);
    bf16* aoH = (bf16*)(ws + SZF);
    bf16* aoL = (bf16*)(ws + SZF + SZP);
    float* att = (float*)(ws + SZF + 2 * SZP);
    bf16* y2H = (bf16*)(ws + SZF);
    bf16* y2L = (bf16*)(ws + SZF + SZP);
    const size_t OQ = SZF + 2 * SZHP;
    bf16* qkvH = (bf16*)(ws + OQ);
    bf16* qkvL = (bf16*)(ws + OQ + SZQP);
    float* y   = (float*)(ws + OQ);
    bf16* ffH  = (bf16*)(ws + OQ + SZF);
    bf16* ffL  = (bf16*)(ws + OQ + SZF + SZFP);
    const size_t OW = OQ + 2 * SZQP;
    bf16* wqH = (bf16*)(ws + OW);
    bf16* wqL = (bf16*)(ws + OW + 3538944);
    bf16* woH = (bf16*)(ws + OW + 2 * 3538944);
    bf16* woL = (bf16*)(ws + OW + 2 * 3538944 + 1179648);
    bf16* w1H = (bf16*)(ws + OW + 2 * 3538944 + 2 * 1179648);
    bf16* w1L = (bf16*)(ws + OW + 2 * 3538944 + 2 * 1179648 + 4718592);
    bf16* w2H = (bf16*)(ws + OW + 2 * 3538944 + 2 * 1179648 + 2 * 4718592);
    bf16* w2L = (bf16*)(ws + OW + 2 * 3538944 + 2 * 1179648 + 3 * 4718592);

    // 0) pre-split weights into hi/lo planes
    split_planes<<<512, 256, 0, stream>>>(w_qkv, wqH, wqL, 1769472);
    split_planes<<<512, 256, 0, stream>>>(w_out, woH, woL, 589824);
    split_planes<<<512, 256, 0, stream>>>(w1,    w1H, w1L, 2359296);
    split_planes<<<512, 256, 0, stream>>>(w2,    w2H, w2L, 2359296);

    // 1) LN1 + LN_att
    prep_ln<<<6272, 256, 0, stream>>>(x, memory, ln1_g, ln1_b, ln_att_g, ln_att_b, xres, hH, hL);

    // 2) qkv planes = h @ w_qkv^T  (M=6272, N=2304, K=768)
    gemm_pl<0><<<dim3(18, 49), 256, 0, stream>>>(hH, hL, wqH, wqL, 6272, 2304, 768,
                                                 nullptr, nullptr, nullptr, qkvH, qkvL);

    // 3) attention  (grid: x = hh+12*b, y = w*4+g  -> XCD-local K/V sharing)
    attn_kernel<<<dim3(48, 16), 256, 0, stream>>>(qkvH, qkvL, aoH, aoL);

    // 4) att = ao @ w_out^T + b_out  (M=3136, N=768, K=768) -> fp32
    gemm_pl<1><<<dim3(6, 25), 256, 0, stream>>>(aoH, aoL, woH, woL, 3136, 768, 768,
                                                b_out, nullptr, att, nullptr, nullptr);

    // 5) y = xres + att ; y2 planes = LN2(y)
    ln2_resid<<<3136, 256, 0, stream>>>(xres, att, ln2_g, ln2_b, y, y2H, y2L);

    // 6) ff planes = silu(y2 @ w1^T + b1)  (M=3136, N=3072, K=768)
    gemm_pl<2><<<dim3(24, 25), 256, 0, stream>>>(y2H, y2L, w1H, w1L, 3136, 3072, 768,
                                                 b1, nullptr, nullptr, ffH, ffL);

    // 7) out = y + ff @ w2^T + b2  (M=3136, N=768, K=3072) -> fp32 d_out
    gemm_pl<3><<<dim3(6, 25), 256, 0, stream>>>(ffH, ffL, w2H, w2L, 3136, 768, 3072,
                                                b2, y, (float*)d_out, nullptr, nullptr);
}

// Round 2
// 477.669 us; speedup vs baseline: 1.2534x; 1.1224x over previous
//
#include <hip/hip_runtime.h>
#include <cstdint>

typedef __bf16 bf16;
typedef __bf16 bf16x8 __attribute__((ext_vector_type(8)));
typedef float f32x4 __attribute__((ext_vector_type(4)));

#define AS1 __attribute__((address_space(1)))
#define AS3 __attribute__((address_space(3)))

// Async global->LDS, 16B per lane. LDS dest must be wave-uniform base;
// HW writes lane i at base + i*16 (m97/m104 semantics).
__device__ __forceinline__ void load16_lds(const void* gp, void* lds_base_wave_uniform) {
    __builtin_amdgcn_global_load_lds((AS1 void*)((void*)gp),
                                     (AS3 void*)lds_base_wave_uniform, 16, 0, 0);
}

// ---------------------------------------------------------------------------
// fp32 -> (hi, lo) bf16 planes.
// ---------------------------------------------------------------------------
__global__ __launch_bounds__(256) void split_planes(const float* __restrict__ src,
                                                    bf16* __restrict__ h,
                                                    bf16* __restrict__ l, int n)
{
    const int stride = gridDim.x * blockDim.x;
    for (int i = blockIdx.x * blockDim.x + threadIdx.x; i < n; i += stride) {
        float v = src[i];
        bf16 hh = (bf16)v;
        h[i] = hh;
        l[i] = (bf16)(v - (float)hh);
    }
}

// ---------------------------------------------------------------------------
// LN1 -> xres (fp32, x rows only); LN_att(LN1) -> h hi/lo planes (all rows).
// ---------------------------------------------------------------------------
__global__ __launch_bounds__(256) void prep_ln(
    const float* __restrict__ x, const float* __restrict__ memory,
    const float* __restrict__ g1, const float* __restrict__ b1,
    const float* __restrict__ ga, const float* __restrict__ ba,
    float* __restrict__ xres, bf16* __restrict__ hH, bf16* __restrict__ hL)
{
    const int row = blockIdx.x;            // 0..6271
    const int b = row / 1568, l = row - b * 1568;
    const float* src = (l < 784) ? (memory + ((size_t)b * 1024 + l) * 768)
                                 : (x + ((size_t)b * 784 + (l - 784)) * 768);
    const int t = threadIdx.x, lane = t & 63, wv = t >> 6;
    __shared__ float red[8];

    float v[3];
#pragma unroll
    for (int i = 0; i < 3; ++i) v[i] = src[i * 256 + t];

    float s = v[0] + v[1] + v[2];
    float s2 = v[0] * v[0] + v[1] * v[1] + v[2] * v[2];
#pragma unroll
    for (int off = 1; off < 64; off <<= 1) { s += __shfl_xor(s, off, 64); s2 += __shfl_xor(s2, off, 64); }
    if (lane == 0) { red[wv] = s; red[4 + wv] = s2; }
    __syncthreads();
    s = red[0] + red[1] + red[2] + red[3];
    s2 = red[4] + red[5] + red[6] + red[7];
    float mu = s * (1.0f / 768.0f);
    float var = s2 * (1.0f / 768.0f) - mu * mu;
    float rs = rsqrtf(fmaxf(var, 0.0f) + 1e-5f);

    float w[3];
#pragma unroll
    for (int i = 0; i < 3; ++i) {
        int c = i * 256 + t;
        w[i] = (v[i] - mu) * rs * g1[c] + b1[c];
    }
    if (l >= 784) {
        float* xr = xres + ((size_t)b * 784 + (l - 784)) * 768;
#pragma unroll
        for (int i = 0; i < 3; ++i) xr[i * 256 + t] = w[i];
    }

    s = w[0] + w[1] + w[2];
    s2 = w[0] * w[0] + w[1] * w[1] + w[2] * w[2];
#pragma unroll
    for (int off = 1; off < 64; off <<= 1) { s += __shfl_xor(s, off, 64); s2 += __shfl_xor(s2, off, 64); }
    __syncthreads();
    if (lane == 0) { red[wv] = s; red[4 + wv] = s2; }
    __syncthreads();
    s = red[0] + red[1] + red[2] + red[3];
    s2 = red[4] + red[5] + red[6] + red[7];
    float mu2 = s * (1.0f / 768.0f);
    float var2 = s2 * (1.0f / 768.0f) - mu2 * mu2;
    float rs2 = rsqrtf(fmaxf(var2, 0.0f) + 1e-5f);

    bf16* hh_ = hH + (size_t)row * 768;
    bf16* hl_ = hL + (size_t)row * 768;
#pragma unroll
    for (int i = 0; i < 3; ++i) {
        int c = i * 256 + t;
        float hv = (w[i] - mu2) * rs2 * ga[c] + ba[c];
        bf16 hvh = (bf16)hv;
        hh_[c] = hvh;
        hl_[c] = (bf16)(hv - (float)hvh);
    }
}

// ---------------------------------------------------------------------------
// Plane GEMM with async global->LDS staging (width 16, m97 pattern).
// C = A*B^T; A/B as bf16 hi/lo planes; 128x128 tile, BK=32, 4 waves x 64x64.
// Split-K via gridDim.z (K-chunk = K/gridDim.z per z-slice).
// MODE 0: planes out (z=1). 1: fp32 partial -> Cf + z*M*N (no bias).
// MODE 2: silu planes out (z=1). 3: atomic fp32 += into prefilled Cf.
// ---------------------------------------------------------------------------
template <int MODE>
__global__ __launch_bounds__(256, 2) void gemm_pl(
    const bf16* __restrict__ Ah, const bf16* __restrict__ Al,
    const bf16* __restrict__ Bh, const bf16* __restrict__ Bl,
    int M, int N, int K,
    const float* __restrict__ bias, const float* __restrict__ resid,
    float* __restrict__ Cf, bf16* __restrict__ Ch, bf16* __restrict__ Cl)
{
    __shared__ __align__(16) bf16 Ahs[128 * 32], Als[128 * 32];
    __shared__ __align__(16) bf16 Bhs[128 * 32], Bls[128 * 32];
    const int t = threadIdx.x, lane = t & 63, wv = t >> 6;
    const int row0 = blockIdx.y * 128, col0 = blockIdx.x * 128;
    const int ro = (wv >> 1) * 64, co = (wv & 1) * 64;
    const int Kc = K / gridDim.z;
    const int kbeg = blockIdx.z * Kc, kend = kbeg + Kc;

    f32x4 acc[4][4] = {};

    for (int k0 = kbeg; k0 < kend; k0 += 32) {
#pragma unroll
        for (int it = 0; it < 2; ++it) {
            int f = it * 256 + t;
            int r = f >> 2, kc = (f & 3) * 8;
            int ra = row0 + r; if (ra >= M) ra = M - 1;
            size_t oa = (size_t)ra * K + k0 + kc;
            size_t ob = (size_t)(col0 + r) * K + k0 + kc;
            // wave-uniform LDS base (lane offset applied by HW: +lane*16B)
            size_t lb = (size_t)(it * 256 + wv * 64) * 8;
            load16_lds(Ah + oa, Ahs + lb);
            load16_lds(Al + oa, Als + lb);
            load16_lds(Bh + ob, Bhs + lb);
            load16_lds(Bl + ob, Bls + lb);
        }
        asm volatile("s_waitcnt vmcnt(0)" ::: "memory");
        __syncthreads();
        bf16x8 ah[4], al[4], bh[4], bl[4];
#pragma unroll
        for (int i = 0; i < 4; ++i) {
            int o = (ro + i * 16 + (lane & 15)) * 32 + (lane >> 4) * 8;
            ah[i] = *(const bf16x8*)&Ahs[o];
            al[i] = *(const bf16x8*)&Als[o];
        }
#pragma unroll
        for (int j = 0; j < 4; ++j) {
            int o = (co + j * 16 + (lane & 15)) * 32 + (lane >> 4) * 8;
            bh[j] = *(const bf16x8*)&Bhs[o];
            bl[j] = *(const bf16x8*)&Bls[o];
        }
#pragma unroll
        for (int i = 0; i < 4; ++i)
#pragma unroll
            for (int j = 0; j < 4; ++j) {
                acc[i][j] = __builtin_amdgcn_mfma_f32_16x16x32_bf16(al[i], bh[j], acc[i][j], 0, 0, 0);
                acc[i][j] = __builtin_amdgcn_mfma_f32_16x16x32_bf16(ah[i], bl[j], acc[i][j], 0, 0, 0);
                acc[i][j] = __builtin_amdgcn_mfma_f32_16x16x32_bf16(ah[i], bh[j], acc[i][j], 0, 0, 0);
            }
        __syncthreads();
    }

    const size_t zoff = (size_t)blockIdx.z * M * N;
#pragma unroll
    for (int i = 0; i < 4; ++i)
#pragma unroll
        for (int j = 0; j < 4; ++j)
#pragma unroll
            for (int r = 0; r < 4; ++r) {
                int row = row0 + ro + i * 16 + (lane >> 4) * 4 + r;
                int col = col0 + co + j * 16 + (lane & 15);
                if (row >= M) continue;
                float v = acc[i][j][r];
                size_t idx = (size_t)row * N + col;
                if (MODE == 0) {
                    bf16 hh = (bf16)v;
                    Ch[idx] = hh; Cl[idx] = (bf16)(v - (float)hh);
                } else if (MODE == 1) {
                    Cf[zoff + idx] = v;               // partial, bias added later
                } else if (MODE == 2) {
                    v += bias[col];
                    v = v / (1.0f + __expf(-v));
                    bf16 hh = (bf16)v;
                    Ch[idx] = hh; Cl[idx] = (bf16)(v - (float)hh);
                } else {
                    unsafeAtomicAdd(&Cf[idx], v);     // HW f32 atomic, prefilled dest
                }
            }
}

// ---------------------------------------------------------------------------
// Flash attention, pipelined. Grid: x = hh + 12*b (48), y = w*4+g (16).
// Deferred softmax (bounded logits), single barrier per K-tile, swizzled K
// via pre-swizzled global_load_lds source, V reg-prefetch + 2-way-bank
// transposed write.
// ---------------------------------------------------------------------------
__global__ __launch_bounds__(256, 3) void attn_kernel(
    const bf16* __restrict__ qh_, const bf16* __restrict__ ql_,
    bf16* __restrict__ oh_, bf16* __restrict__ ol_)
{
    const int hh = blockIdx.x % 12, b = blockIdx.x / 12;
    const int w = blockIdx.y >> 2, g = blockIdx.y & 3;
    const int kmax = (5 + w) * 196, nkt = (kmax + 31) / 32;
    const int t = threadIdx.x, lane = t & 63, wv = t >> 6;
    const int tile = g * 4 + wv;                  // 0..15; >12 idle (wave-uniform)
    const int l15 = lane & 15, q8 = lane >> 4;

    __shared__ __align__(16) bf16 Ks_h[2][32 * 64], Ks_l[2][32 * 64];
    __shared__ __align__(16) bf16 Vt_h[2][64 * 40];
    __shared__ __align__(16) bf16 Pl_h[4][16 * 40];

    const size_t bbase = (size_t)b * 1568 * 2304;

    // staging geometry: thread t covers K/V row srow, col chunk sc8.
    const int srow = t >> 3;                      // 0..31 (wave wv: rows wv*8..+7)
    const int sc8 = (t & 7) * 8;
    // K: LDS dest is linear (global_load_lds), so pre-swizzle the SOURCE col.
    const int scsrc = sc8 ^ ((srow & 7) * 8);

    // Q fragments (held in registers for the whole kernel)
    int tcl = tile > 12 ? 12 : tile;
    int qr0 = tcl * 16 + l15; if (qr0 > 195) qr0 = 195;
    const size_t qoff = bbase + (size_t)(784 + w * 196 + qr0) * 2304 + hh * 64 + q8 * 8;
    bf16x8 qfh[2], qfl[2];
#pragma unroll
    for (int p = 0; p < 2; ++p) {
        qfh[p] = *(const bf16x8*)(qh_ + qoff + p * 32);
        qfl[p] = *(const bf16x8*)(ql_ + qoff + p * 32);
    }

    float l_i[4] = {0.f, 0.f, 0.f, 0.f};
    f32x4 oacc[4];
#pragma unroll
    for (int nd = 0; nd < 4; ++nd) oacc[nd] = f32x4{0.f, 0.f, 0.f, 0.f};

    // issue staging for K-tile kt2 into buffer bufn; V -> vreg (not yet in LDS)
    auto stage_issue = [&](int kt2, int bufn, bf16x8& vreg) {
        const size_t kb = bbase + (size_t)(kt2 * 32 + srow) * 2304 + 768 + (size_t)hh * 64;
        load16_lds(qh_ + kb + scsrc, &Ks_h[bufn][wv * 512]);
        load16_lds(ql_ + kb + scsrc, &Ks_l[bufn][wv * 512]);
        vreg = *(const bf16x8*)(qh_ + kb + 768 + sc8);
    };
    // transposed V write, key-XOR swizzled (2-way banks instead of 16-way)
    auto write_V = [&](int bufn, const bf16x8& vreg) {
#pragma unroll
        for (int j = 0; j < 8; ++j) {
            int d = sc8 + j;
            int keyx = srow ^ (((d >> 3) & 3) * 8);
            Vt_h[bufn][d * 40 + keyx] = vreg[j];
        }
    };

    // ---- prologue: stage tile 0 into buffer 0
    {
        bf16x8 v0;
        stage_issue(0, 0, v0);
        write_V(0, v0);                            // data dep inserts vmcnt wait
        asm volatile("s_waitcnt vmcnt(0)" ::: "memory");
        __syncthreads();
    }

    const float CEXP = 0.18033688011112042f;       // 0.125 * log2(e)

    for (int kt = 0; kt < nkt; ++kt) {
        const int cur = kt & 1, nxt = cur ^ 1;
        int kt2 = kt + 1; if (kt2 >= nkt) kt2 = nkt - 1;   // clamp (no OOB)
        bf16x8 vnext;
        stage_issue(kt2, nxt, vnext);              // overlaps with compute below

        if (tile <= 12) {
            bf16x8 kfh[2][2], kfl[2][2], vth[4];
#pragma unroll
            for (int nb = 0; nb < 2; ++nb)
#pragma unroll
                for (int p = 0; p < 2; ++p) {
                    int row = nb * 16 + l15;
                    int c = (p * 32 + q8 * 8) ^ ((row & 7) * 8);
                    kfh[nb][p] = *(const bf16x8*)&Ks_h[cur][row * 64 + c];
                    kfl[nb][p] = *(const bf16x8*)&Ks_l[cur][row * 64 + c];
                }
#pragma unroll
            for (int nd = 0; nd < 4; ++nd) {
                int d = nd * 16 + l15;
                int k8 = (q8 * 8) ^ (((d >> 3) & 3) * 8);
                vth[nd] = *(const bf16x8*)&Vt_h[cur][d * 40 + k8];
            }

            // QK^T: 4 independent depth-3 MFMA chains
            f32x4 s0a = {0.f,0.f,0.f,0.f}, s0b = {0.f,0.f,0.f,0.f};
            f32x4 s1a = {0.f,0.f,0.f,0.f}, s1b = {0.f,0.f,0.f,0.f};
            s0a = __builtin_amdgcn_mfma_f32_16x16x32_bf16(qfl[0], kfh[0][0], s0a, 0, 0, 0);
            s1a = __builtin_amdgcn_mfma_f32_16x16x32_bf16(qfl[0], kfh[1][0], s1a, 0, 0, 0);
            s0b = __builtin_amdgcn_mfma_f32_16x16x32_bf16(qfl[1], kfh[0][1], s0b, 0, 0, 0);
            s1b = __builtin_amdgcn_mfma_f32_16x16x32_bf16(qfl[1], kfh[1][1], s1b, 0, 0, 0);
            s0a = __builtin_amdgcn_mfma_f32_16x16x32_bf16(qfh[0], kfl[0][0], s0a, 0, 0, 0);
            s1a = __builtin_amdgcn_mfma_f32_16x16x32_bf16(qfh[0], kfl[1][0], s1a, 0, 0, 0);
            s0b = __builtin_amdgcn_mfma_f32_16x16x32_bf16(qfh[1], kfl[0][1], s0b, 0, 0, 0);
            s1b = __builtin_amdgcn_mfma_f32_16x16x32_bf16(qfh[1], kfl[1][1], s1b, 0, 0, 0);
            s0a = __builtin_amdgcn_mfma_f32_16x16x32_bf16(qfh[0], kfh[0][0], s0a, 0, 0, 0);
            s1a = __builtin_amdgcn_mfma_f32_16x16x32_bf16(qfh[0], kfh[1][0], s1a, 0, 0, 0);
            s0b = __builtin_amdgcn_mfma_f32_16x16x32_bf16(qfh[1], kfh[0][1], s0b, 0, 0, 0);
            s1b = __builtin_amdgcn_mfma_f32_16x16x32_bf16(qfh[1], kfh[1][1], s1b, 0, 0, 0);
            f32x4 s0 = s0a + s0b, s1 = s1a + s1b;

            // deferred softmax: p = exp(S/8), no max subtraction, no rescale
            const int key0 = kt * 32 + l15;
            const bool m0 = (key0 >= kmax), m1 = (key0 + 16 >= kmax);
#pragma unroll
            for (int r = 0; r < 4; ++r) {
                float p0 = m0 ? 0.0f : exp2f(s0[r] * CEXP);
                float p1 = m1 ? 0.0f : exp2f(s1[r] * CEXP);
                l_i[r] += p0 + p1;
                int pr = q8 * 4 + r;
                Pl_h[wv][pr * 40 + l15] = (bf16)p0;
                Pl_h[wv][pr * 40 + 16 + l15] = (bf16)p1;
            }
            asm volatile("s_waitcnt lgkmcnt(0)" ::: "memory");   // wave-private Pl RAW
            bf16x8 pfh = *(const bf16x8*)&Pl_h[wv][l15 * 40 + q8 * 8];
#pragma unroll
            for (int nd = 0; nd < 4; ++nd)
                oacc[nd] = __builtin_amdgcn_mfma_f32_16x16x32_bf16(pfh, vth[nd], oacc[nd], 0, 0, 0);
        }

        write_V(nxt, vnext);                       // waits vmcnt for vnext only here
        asm volatile("s_waitcnt vmcnt(0)" ::: "memory");
        __syncthreads();
    }

    if (tile <= 12) {
#pragma unroll
        for (int r = 0; r < 4; ++r) {
            float s = l_i[r];
#pragma unroll
            for (int off = 1; off < 16; off <<= 1) s += __shfl_xor(s, off, 64);
            int qr = tile * 16 + q8 * 4 + r;
            if (qr >= 196) continue;
            float inv = 1.0f / s;
            size_t row = (size_t)b * 784 + w * 196 + qr;
#pragma unroll
            for (int nd = 0; nd < 4; ++nd) {
                float ov = oacc[nd][r] * inv;
                bf16 oh = (bf16)ov;
                size_t idx = row * 768 + hh * 64 + nd * 16 + l15;
                oh_[idx] = oh;
                ol_[idx] = (bf16)(ov - (float)oh);
            }
        }
    }
}

// ---------------------------------------------------------------------------
// y = xres + p0 + p1 + b_out (fp32), y2 = LN2(y) planes, dout = y + b2ff
// (prefill for the atomic split-K w2 GEMM). Block per x-row (3136).
// ---------------------------------------------------------------------------
__global__ __launch_bounds__(256) void ln2_resid(
    const float* __restrict__ xres, const float* __restrict__ attP,
    const float* __restrict__ bo,
    const float* __restrict__ g2, const float* __restrict__ b2,
    const float* __restrict__ b2ff,
    float* __restrict__ y, bf16* __restrict__ y2H, bf16* __restrict__ y2L,
    float* __restrict__ dout)
{
    const int row = blockIdx.x;
    const size_t MN = (size_t)3136 * 768;
    const float* xr = xres + (size_t)row * 768;
    const float* a0 = attP + (size_t)row * 768;
    const float* a1 = attP + MN + (size_t)row * 768;
    const int t = threadIdx.x, lane = t & 63, wv = t >> 6;
    __shared__ float red[8];

    float v[3];
    float* yr = y + (size_t)row * 768;
    float* dr = dout + (size_t)row * 768;
#pragma unroll
    for (int i = 0; i < 3; ++i) {
        int c = i * 256 + t;
        v[i] = xr[c] + a0[c] + a1[c] + bo[c];
        yr[c] = v[i];
        dr[c] = v[i] + b2ff[c];
    }
    float s = v[0] + v[1] + v[2];
    float s2 = v[0] * v[0] + v[1] * v[1] + v[2] * v[2];
#pragma unroll
    for (int off = 1; off < 64; off <<= 1) { s += __shfl_xor(s, off, 64); s2 += __shfl_xor(s2, off, 64); }
    if (lane == 0) { red[wv] = s; red[4 + wv] = s2; }
    __syncthreads();
    s = red[0] + red[1] + red[2] + red[3];
    s2 = red[4] + red[5] + red[6] + red[7];
    float mu = s * (1.0f / 768.0f);
    float var = s2 * (1.0f / 768.0f) - mu * mu;
    float rs = rsqrtf(fmaxf(var, 0.0f) + 1e-5f);

    bf16* yh = y2H + (size_t)row * 768;
    bf16* yl = y2L + (size_t)row * 768;
#pragma unroll
    for (int i = 0; i < 3; ++i) {
        int c = i * 256 + t;
        float yv = (v[i] - mu) * rs * g2[c] + b2[c];
        bf16 yvh = (bf16)yv;
        yh[c] = yvh;
        yl[c] = (bf16)(yv - (float)yvh);
    }
}

// ---------------------------------------------------------------------------
extern "C" void kernel_launch(void* const* d_in, const int* in_sizes, int n_in,
                              void* d_out, int out_size, void* d_ws, size_t ws_size,
                              hipStream_t stream)
{
    (void)in_sizes; (void)n_in; (void)out_size; (void)ws_size;
    const float* x        = (const float*)d_in[0];
    const float* memory   = (const float*)d_in[1];
    const float* ln_att_g = (const float*)d_in[2];
    const float* ln_att_b = (const float*)d_in[3];
    const float* w_qkv    = (const float*)d_in[4];
    const float* w_out    = (const float*)d_in[5];
    const float* b_out    = (const float*)d_in[6];
    const float* ln1_g    = (const float*)d_in[7];
    const float* ln1_b    = (const float*)d_in[8];
    const float* ln2_g    = (const float*)d_in[9];
    const float* ln2_b    = (const float*)d_in[10];
    const float* w1       = (const float*)d_in[11];
    const float* b1       = (const float*)d_in[12];
    const float* w2       = (const float*)d_in[13];
    const float* b2       = (const float*)d_in[14];

    // ---- workspace layout (~109.7 MiB, same footprint) ----
    char* ws = (char*)d_ws;
    const size_t SZF  = (size_t)3136 * 768 * 4;
    const size_t SZP  = (size_t)3136 * 768 * 2;
    const size_t SZHP = (size_t)6272 * 768 * 2;
    const size_t SZQP = (size_t)6272 * 2304 * 2;
    const size_t SZFP = (size_t)3136 * 3072 * 2;

    float* xres = (float*)(ws);
    bf16* hH  = (bf16*)(ws + SZF);
    bf16* hL  = (bf16*)(ws + SZF + SZHP);
    bf16* aoH = (bf16*)(ws + SZF);
    bf16* aoL = (bf16*)(ws + SZF + SZP);
    bf16* y2H = (bf16*)(ws + SZF);
    bf16* y2L = (bf16*)(ws + SZF + SZP);
    const size_t OQ = SZF + 2 * SZHP;
    bf16* qkvH = (bf16*)(ws + OQ);
    bf16* qkvL = (bf16*)(ws + OQ + SZQP);
    float* y    = (float*)(ws + OQ);
    float* attP = (float*)(ws + OQ + SZF);   // 2 partials (dead qkv region; ffH overwrites later)
    bf16* ffH  = (bf16*)(ws + OQ + SZF);
    bf16* ffL  = (bf16*)(ws + OQ + SZF + SZFP);
    const size_t OW = OQ + 2 * SZQP;
    bf16* wqH = (bf16*)(ws + OW);
    bf16* wqL = (bf16*)(ws + OW + 3538944);
    bf16* woH = (bf16*)(ws + OW + 2 * 3538944);
    bf16* woL = (bf16*)(ws + OW + 2 * 3538944 + 1179648);
    bf16* w1H = (bf16*)(ws + OW + 2 * 3538944 + 2 * 1179648);
    bf16* w1L = (bf16*)(ws + OW + 2 * 3538944 + 2 * 1179648 + 4718592);
    bf16* w2H = (bf16*)(ws + OW + 2 * 3538944 + 2 * 1179648 + 2 * 4718592);
    bf16* w2L = (bf16*)(ws + OW + 2 * 3538944 + 2 * 1179648 + 3 * 4718592);

    // 0) pre-split weights into hi/lo planes
    split_planes<<<512, 256, 0, stream>>>(w_qkv, wqH, wqL, 1769472);
    split_planes<<<512, 256, 0, stream>>>(w_out, woH, woL, 589824);
    split_planes<<<512, 256, 0, stream>>>(w1,    w1H, w1L, 2359296);
    split_planes<<<512, 256, 0, stream>>>(w2,    w2H, w2L, 2359296);

    // 1) LN1 + LN_att
    prep_ln<<<6272, 256, 0, stream>>>(x, memory, ln1_g, ln1_b, ln_att_g, ln_att_b, xres, hH, hL);

    // 2) qkv planes = h @ w_qkv^T  (M=6272, N=2304, K=768)
    gemm_pl<0><<<dim3(18, 49), 256, 0, stream>>>(hH, hL, wqH, wqL, 6272, 2304, 768,
                                                 nullptr, nullptr, nullptr, qkvH, qkvL);

    // 3) attention  (grid: x = hh+12*b, y = w*4+g  -> XCD-local K/V sharing)
    attn_kernel<<<dim3(48, 16), 256, 0, stream>>>(qkvH, qkvL, aoH, aoL);

    // 4) att partials = ao @ w_out^T  (M=3136, N=768, K=768, split-K=2 -> 300 blocks)
    gemm_pl<1><<<dim3(6, 25, 2), 256, 0, stream>>>(aoH, aoL, woH, woL, 3136, 768, 768,
                                                   nullptr, nullptr, attP, nullptr, nullptr);

    // 5) y = xres + p0 + p1 + b_out ; y2 planes = LN2(y) ; dout prefill = y + b2
    ln2_resid<<<3136, 256, 0, stream>>>(xres, attP, b_out, ln2_g, ln2_b, b2,
                                        y, y2H, y2L, (float*)d_out);

    // 6) ff planes = silu(y2 @ w1^T + b1)  (M=3136, N=3072, K=768)
    gemm_pl<2><<<dim3(24, 25), 256, 0, stream>>>(y2H, y2L, w1H, w1L, 3136, 3072, 768,
                                                 b1, nullptr, nullptr, ffH, ffL);

    // 7) d_out += ff @ w2^T  (M=3136, N=768, K=3072, split-K=4 -> 600 blocks, atomic)
    gemm_pl<3><<<dim3(6, 25, 4), 256, 0, stream>>>(ffH, ffL, w2H, w2L, 3136, 768, 3072,
                                                   nullptr, nullptr, (float*)d_out, nullptr, nullptr);
}